// Round 1
// baseline (57.714 us; speedup 1.0000x reference)
//
#include <hip/hip_runtime.h>

typedef __attribute__((ext_vector_type(4))) float f32x4;
typedef __attribute__((ext_vector_type(8))) short bf16x8;

// f32 -> bf16 round-to-nearest-even
__device__ inline unsigned short f2bf(float x) {
  unsigned u = __builtin_bit_cast(unsigned, x);
  u += 0x7fffu + ((u >> 16) & 1u);
  return (unsigned short)(u >> 16);
}

// load 8 contiguous f32, convert to bf16x8 fragment
__device__ inline bf16x8 cvt8(const float* __restrict__ p) {
  f32x4 lo = *(const f32x4*)p;
  f32x4 hi = *(const f32x4*)(p + 4);
  bf16x8 r;
  r[0] = (short)f2bf(lo[0]); r[1] = (short)f2bf(lo[1]);
  r[2] = (short)f2bf(lo[2]); r[3] = (short)f2bf(lo[3]);
  r[4] = (short)f2bf(hi[0]); r[5] = (short)f2bf(hi[1]);
  r[6] = (short)f2bf(hi[2]); r[7] = (short)f2bf(hi[3]);
  return r;
}

// GEMM1: e[2048][128] = X[2048][768] @ Wr[128][768]^T + br, output bf16
// wave computes one 16x16 tile; A row = lane&15 (token), B col = lane&15 (r)
__global__ __launch_bounds__(256) void gemm1_kernel(
    const float* __restrict__ X, const float* __restrict__ Wr,
    const float* __restrict__ br, unsigned short* __restrict__ Ebf) {
  int wave = threadIdx.x >> 6;
  int lane = threadIdx.x & 63;
  int t0 = (blockIdx.x * 4 + wave) * 16;   // token tile base
  int n0 = blockIdx.y * 16;                // r tile base
  int lrow = lane & 15;
  int kgrp = (lane >> 4) * 8;
  const float* arow = X + (size_t)(t0 + lrow) * 768 + kgrp;
  const float* brow = Wr + (size_t)(n0 + lrow) * 768 + kgrp;
  f32x4 acc = {0.f, 0.f, 0.f, 0.f};
  for (int k0 = 0; k0 < 768; k0 += 32) {
    bf16x8 a = cvt8(arow + k0);
    bf16x8 b = cvt8(brow + k0);
    acc = __builtin_amdgcn_mfma_f32_16x16x32_bf16(a, b, acc, 0, 0, 0);
  }
  int cn = lane & 15;              // col = r index
  int rbase = (lane >> 4) * 4;     // row = token
  float bias = br[n0 + cn];
#pragma unroll
  for (int r = 0; r < 4; ++r) {
    float val = acc[r] + bias;
    Ebf[(size_t)(t0 + rbase + r) * 128 + n0 + cn] = f2bf(val);
  }
}

// GEMM2: UVt[512][2048]; rows 0..255 = u'(= e@W1_row^T + b1), 256..511 = v
// A[m][k] = W1[m][k] (m<256) or W1[m-256][128+k]; B[k][t] = e[t][k] (bf16)
__global__ __launch_bounds__(256) void gemm2_kernel(
    const unsigned short* __restrict__ Ebf, const float* __restrict__ W1,
    const float* __restrict__ b1, float* __restrict__ UVt) {
  int wave = threadIdx.x >> 6;
  int lane = threadIdx.x & 63;
  int t0 = blockIdx.x * 64 + wave * 16;    // token tile base
  int m0 = blockIdx.y * 16;                // m-output tile base (0..511)
  int lidx = lane & 15;
  int kg = (lane >> 4) * 8;
  const float* aBase = (m0 < 256)
      ? (W1 + (size_t)(m0 + lidx) * 256 + kg)
      : (W1 + (size_t)(m0 - 256 + lidx) * 256 + 128 + kg);
  const unsigned short* bBase = Ebf + (size_t)(t0 + lidx) * 128 + kg;
  f32x4 acc = {0.f, 0.f, 0.f, 0.f};
  for (int k0 = 0; k0 < 128; k0 += 32) {
    bf16x8 a = cvt8(aBase + k0);
    bf16x8 b = *(const bf16x8*)(const void*)(bBase + k0);
    acc = __builtin_amdgcn_mfma_f32_16x16x32_bf16(a, b, acc, 0, 0, 0);
  }
  int ct = lane & 15;
  int rb = (lane >> 4) * 4;
#pragma unroll
  for (int r = 0; r < 4; ++r) {
    int m = m0 + rb + r;
    float bias = (m < 256) ? b1[m] : 0.f;
    UVt[(size_t)m * 2048 + t0 + ct] = acc[r] + bias;
  }
}

// Pairwise: out[b,i,j]; only upper-triangular 32x32 tile pairs computed,
// mirrored via LDS transpose bounce. 256 thr, each 2x2 outputs.
__global__ __launch_bounds__(256) void pairwise_kernel(
    const float* __restrict__ UVt, const float* __restrict__ W2,
    const float* __restrict__ b2p, float* __restrict__ Out) {
  __shared__ float u_lds[64][32];
  __shared__ float v_lds[64][32];
  __shared__ float w2_lds[256];
  __shared__ float t_lds[32][36];

  int tid = threadIdx.x;
  int b = blockIdx.y;
  // decode triangular pair index -> (it, jt), it <= jt, 32 tiles per dim
  int p = blockIdx.x;
  int it = 0;
  while (p >= 32 - it) { p -= 32 - it; ++it; }
  int jt = it + p;

  w2_lds[tid] = W2[tid];

  int tx = tid & 15, ty = tid >> 4;
  int q = tid & 7, row = tid >> 3;
  int utok = b * 1024 + it * 32;
  int vtok = b * 1024 + jt * 32;

  float acc00 = 0.f, acc01 = 0.f, acc10 = 0.f, acc11 = 0.f;

  for (int mc = 0; mc < 4; ++mc) {
    __syncthreads();
#pragma unroll
    for (int ph = 0; ph < 2; ++ph) {
      int ml = row + 32 * ph;
      int mg = mc * 64 + ml;
      f32x4 uu = *(const f32x4*)(UVt + (size_t)mg * 2048 + utok + 4 * q);
      f32x4 vv = *(const f32x4*)(UVt + (size_t)(256 + mg) * 2048 + vtok + 4 * q);
      *(f32x4*)&u_lds[ml][4 * q] = uu;
      *(f32x4*)&v_lds[ml][4 * q] = vv;
    }
    __syncthreads();
    for (int mm = 0; mm < 64; mm += 4) {
      f32x4 w2v = *(const f32x4*)&w2_lds[mc * 64 + mm];
#pragma unroll
      for (int t = 0; t < 4; ++t) {
        float u0 = u_lds[mm + t][2 * ty];
        float u1 = u_lds[mm + t][2 * ty + 1];
        float v0 = v_lds[mm + t][2 * tx];
        float v1 = v_lds[mm + t][2 * tx + 1];
        float w = w2v[t];
        acc00 = fmaf(fmaxf(u0 + v0, 0.f), w, acc00);
        acc01 = fmaf(fmaxf(u0 + v1, 0.f), w, acc01);
        acc10 = fmaf(fmaxf(u1 + v0, 0.f), w, acc10);
        acc11 = fmaf(fmaxf(u1 + v1, 0.f), w, acc11);
      }
    }
  }

  float b2v = b2p[0];
  __syncthreads();
  t_lds[2 * ty][2 * tx] = acc00 + b2v;
  t_lds[2 * ty][2 * tx + 1] = acc01 + b2v;
  t_lds[2 * ty + 1][2 * tx] = acc10 + b2v;
  t_lds[2 * ty + 1][2 * tx + 1] = acc11 + b2v;
  __syncthreads();

  int il = tid >> 3;   // 0..31
  int jq = tid & 7;    // float4 group
  size_t obase = (size_t)b << 20;  // b * 1024*1024
  if (it != jt) {
    f32x4 dv, mv;
#pragma unroll
    for (int k = 0; k < 4; ++k) dv[k] = t_lds[il][4 * jq + k];
    *(f32x4*)(Out + obase + (size_t)(it * 32 + il) * 1024 + jt * 32 + 4 * jq) = dv;
#pragma unroll
    for (int k = 0; k < 4; ++k) mv[k] = t_lds[4 * jq + k][il];
    *(f32x4*)(Out + obase + (size_t)(jt * 32 + il) * 1024 + it * 32 + 4 * jq) = mv;
  } else {
#pragma unroll
    for (int k = 0; k < 4; ++k) {
      int jl = 4 * jq + k;
      float v = t_lds[il][jl];
      if (jl >= il) Out[obase + (size_t)(it * 32 + il) * 1024 + jt * 32 + jl] = v;
      if (jl > il)  Out[obase + (size_t)(jt * 32 + jl) * 1024 + it * 32 + il] = v;
    }
  }
}

extern "C" void kernel_launch(void* const* d_in, const int* in_sizes, int n_in,
                              void* d_out, int out_size, void* d_ws, size_t ws_size,
                              hipStream_t stream) {
  (void)in_sizes; (void)n_in; (void)out_size; (void)ws_size;
  const float* X  = (const float*)d_in[0];
  const float* Wr = (const float*)d_in[1];
  const float* br = (const float*)d_in[2];
  const float* W1 = (const float*)d_in[3];
  const float* b1 = (const float*)d_in[4];
  const float* W2 = (const float*)d_in[5];
  const float* b2 = (const float*)d_in[6];
  float* Out = (float*)d_out;

  unsigned short* Ebf = (unsigned short*)d_ws;                   // 2048*128 bf16 = 512 KiB
  float* UVt = (float*)((char*)d_ws + (size_t)2048 * 128 * 2);   // 512*2048 f32 = 4 MiB

  gemm1_kernel<<<dim3(32, 8), 256, 0, stream>>>(X, Wr, br, Ebf);
  gemm2_kernel<<<dim3(32, 32), 256, 0, stream>>>(Ebf, W1, b1, UVt);
  pairwise_kernel<<<dim3(528, 2), 256, 0, stream>>>(UVt, W2, b2, Out);
}